// Round 1
// baseline (4261.939 us; speedup 1.0000x reference)
//
#include <hip/hip_runtime.h>
#include <stdint.h>

#define BATCH  1024
#define SEQLEN 15
#define NGATE  2048
#define NVOCAB 11998
#define FEATS  4096

// ---------------------------------------------------------------------------
// prep: Wcat = [W_ih | W_hh] (rows of 1024), bsum = b_ih + b_hh, words = 1
// ---------------------------------------------------------------------------
__global__ void prep_kernel(const float* __restrict__ W_ih, const float* __restrict__ W_hh,
                            const float* __restrict__ b_ih, const float* __restrict__ b_hh,
                            float* __restrict__ Wcat, float* __restrict__ bsum,
                            int* __restrict__ words) {
    int idx = blockIdx.x * 256 + threadIdx.x;
    if (idx < NGATE * 1024) {
        int n = idx >> 10, k = idx & 1023;
        Wcat[idx] = (k < 512) ? W_ih[n * 512 + k] : W_hh[n * 512 + (k - 512)];
    }
    if (idx < NGATE) bsum[idx] = b_ih[idx] + b_hh[idx];
    if (idx < BATCH) words[idx] = 1;
}

// ---------------------------------------------------------------------------
// Tiled fp32 NT GEMM: C[M,N] = A[M,K(lda)] * B[N,K]^T (+bias epilogues)
// BM=BN=64, BK=16, 256 threads, 4x4 microtile.
// MODE 0: C = acc + bias     MODE 1: C = relu(acc + bias)
// MODE 2: fused bias + per-row argmax via packed u64 atomicMax (no C store)
// M must be a multiple of 64 (always 1024 here); N guarded.
// ---------------------------------------------------------------------------
template<int MODE>
__global__ __launch_bounds__(256) void gemm_nt(
    const float* __restrict__ A, int lda,
    const float* __restrict__ Bm,
    const float* __restrict__ bias,
    float* __restrict__ C, int ldc,
    unsigned long long* __restrict__ packed,
    int N, int K)
{
    __shared__ __align__(16) float As[16][68];
    __shared__ __align__(16) float Bs[16][68];
    const int tid = threadIdx.x;
    const int bm = blockIdx.y * 64;
    const int bn = blockIdx.x * 64;
    const int tx = tid & 15, ty = tid >> 4;
    const int lrow = tid >> 2;        // 0..63
    const int lk4  = (tid & 3) << 2;  // 0,4,8,12

    float acc[4][4] = {};

    const float* Aptr = A + (size_t)(bm + lrow) * lda + lk4;
    const int    brow = bn + lrow;
    const float* Bptr = Bm + (size_t)brow * K + lk4;
    const bool   bok  = (brow < N);

    for (int k0 = 0; k0 < K; k0 += 16) {
        float4 av = *(const float4*)(Aptr + k0);
        float4 bv = make_float4(0.f, 0.f, 0.f, 0.f);
        if (bok) bv = *(const float4*)(Bptr + k0);
        __syncthreads();
        As[lk4 + 0][lrow] = av.x;  As[lk4 + 1][lrow] = av.y;
        As[lk4 + 2][lrow] = av.z;  As[lk4 + 3][lrow] = av.w;
        Bs[lk4 + 0][lrow] = bv.x;  Bs[lk4 + 1][lrow] = bv.y;
        Bs[lk4 + 2][lrow] = bv.z;  Bs[lk4 + 3][lrow] = bv.w;
        __syncthreads();
        #pragma unroll
        for (int k = 0; k < 16; ++k) {
            float4 a4 = *(const float4*)(&As[k][ty << 2]);
            float4 b4 = *(const float4*)(&Bs[k][tx << 2]);
            float ar[4] = {a4.x, a4.y, a4.z, a4.w};
            float br[4] = {b4.x, b4.y, b4.z, b4.w};
            #pragma unroll
            for (int i = 0; i < 4; ++i)
                #pragma unroll
                for (int j = 0; j < 4; ++j)
                    acc[i][j] = fmaf(ar[i], br[j], acc[i][j]);
        }
    }

    if (MODE == 0 || MODE == 1) {
        #pragma unroll
        for (int i = 0; i < 4; ++i) {
            int m = bm + (ty << 2) + i;
            #pragma unroll
            for (int j = 0; j < 4; ++j) {
                int n = bn + (tx << 2) + j;
                if (n < N) {
                    float v = acc[i][j] + bias[n];
                    if (MODE == 1) v = fmaxf(v, 0.f);
                    C[(size_t)m * ldc + n] = v;
                }
            }
        }
    } else {
        // fused argmax: monotonic float key in high 32, complemented index in
        // low 32 so atomicMax == (max value, first index on ties) = np.argmax.
        #pragma unroll
        for (int i = 0; i < 4; ++i) {
            unsigned long long best = 0ull;
            #pragma unroll
            for (int j = 0; j < 4; ++j) {
                int n = bn + (tx << 2) + j;
                if (n < N) {
                    float v = acc[i][j] + bias[n];
                    unsigned int u   = __float_as_uint(v);
                    unsigned int key = (u & 0x80000000u) ? ~u : (u | 0x80000000u);
                    unsigned long long p =
                        ((unsigned long long)key << 32) |
                        (unsigned long long)(0xFFFFFFFFu - (unsigned)n);
                    best = (p > best) ? p : best;
                }
            }
            // reduce across the 16 lanes (tx) sharing this row
            #pragma unroll
            for (int s = 1; s < 16; s <<= 1) {
                unsigned long long o = __shfl_xor(best, s, 64);
                best = (o > best) ? o : best;
            }
            if (tx == 0) {
                int m = bm + (ty << 2) + i;
                atomicMax(&packed[m], best);
            }
        }
    }
}

// ---------------------------------------------------------------------------
// LSTM pointwise: gates[B,2048] (i,f,g,o, bias already added) -> c, h
// h written into xh[:,512:1024]; also zeroes packed[] for the next argmax.
// ---------------------------------------------------------------------------
template<bool PRIME>
__global__ void lstm_pw(const float* __restrict__ gates, float* __restrict__ cbuf,
                        float* __restrict__ xh, unsigned long long* __restrict__ packed) {
    int idx = blockIdx.x * 256 + threadIdx.x;  // over 1024*512
    int b = idx >> 9, j = idx & 511;
    const float* g = gates + (size_t)b * NGATE;
    float gi = g[j], gf = g[512 + j], gg = g[1024 + j], go = g[1536 + j];
    float si = 1.f / (1.f + expf(-gi));
    float sf = 1.f / (1.f + expf(-gf));
    float so = 1.f / (1.f + expf(-go));
    float tg = tanhf(gg);
    float cn = PRIME ? (si * tg) : (sf * cbuf[idx] + si * tg);
    cbuf[idx] = cn;
    xh[(size_t)b * 1024 + 512 + j] = so * tanhf(cn);
    if (j == 0) packed[b] = 0ull;
}

// ---------------------------------------------------------------------------
// embedding gather into xh[:,0:512]
// ---------------------------------------------------------------------------
__global__ void gather_emb(const float* __restrict__ emb, const int* __restrict__ words,
                           float* __restrict__ xh) {
    int idx = blockIdx.x * 256 + threadIdx.x;   // 1024*128
    int b = idx >> 7, j4 = (idx & 127) << 2;
    float4 v = *(const float4*)(emb + (size_t)words[b] * 512 + j4);
    *(float4*)(xh + (size_t)b * 1024 + j4) = v;
}

// ---------------------------------------------------------------------------
// finalize one step: unpack argmax, emit token, set next word id
// ---------------------------------------------------------------------------
__global__ void finalize_step(const unsigned long long* __restrict__ packed,
                              int* __restrict__ words, int* __restrict__ out, int t) {
    int b = blockIdx.x * 256 + threadIdx.x;
    if (b < BATCH) {
        unsigned long long p = packed[b];
        int idx = (int)(0xFFFFFFFFu - (unsigned)(p & 0xFFFFFFFFull));
        out[b * SEQLEN + t] = idx;
        words[b] = idx + 2;
    }
}

extern "C" void kernel_launch(void* const* d_in, const int* in_sizes, int n_in,
                              void* d_out, int out_size, void* d_ws, size_t ws_size,
                              hipStream_t stream) {
    const float* img     = (const float*)d_in[0];
    const float* W_feats = (const float*)d_in[1];
    const float* b_feats = (const float*)d_in[2];
    const float* W_ih    = (const float*)d_in[3];
    const float* W_hh    = (const float*)d_in[4];
    const float* b_ih    = (const float*)d_in[5];
    const float* b_hh    = (const float*)d_in[6];
    const float* emb     = (const float*)d_in[7];
    const float* W_out   = (const float*)d_in[8];
    const float* b_out   = (const float*)d_in[9];
    int* out = (int*)d_out;

    float* ws      = (float*)d_ws;
    float* Wcat    = ws;                          // 2048*1024
    float* bsum    = Wcat + 2048 * 1024;          // 2048
    float* img_vec = bsum + 2048;                 // 1024*512
    float* xh      = img_vec + 1024 * 512;        // 1024*1024  [x | h]
    float* gates   = xh + 1024 * 1024;            // 1024*2048
    float* cbuf    = gates + 1024 * 2048;         // 1024*512
    unsigned long long* packed = (unsigned long long*)(cbuf + 1024 * 512);  // 1024
    int* words = (int*)(packed + 1024);           // 1024

    prep_kernel<<<8192, 256, 0, stream>>>(W_ih, W_hh, b_ih, b_hh, Wcat, bsum, words);

    // img_vec = relu(img @ W_feats^T + b_feats)   M=1024 N=512 K=4096
    gemm_nt<1><<<dim3(8, 16), 256, 0, stream>>>(img, FEATS, W_feats, b_feats,
                                                img_vec, 512, nullptr, 512, FEATS);

    // prime LSTM: gates = img_vec @ W_ih^T + (b_ih + b_hh)   N=2048 K=512
    gemm_nt<0><<<dim3(32, 16), 256, 0, stream>>>(img_vec, 512, W_ih, bsum,
                                                 gates, NGATE, nullptr, NGATE, 512);
    lstm_pw<true><<<2048, 256, 0, stream>>>(gates, cbuf, xh, packed);

    for (int t = 0; t < SEQLEN; ++t) {
        gather_emb<<<512, 256, 0, stream>>>(emb, words, xh);
        // gates = [x|h] @ [W_ih|W_hh]^T + bsum   N=2048 K=1024
        gemm_nt<0><<<dim3(32, 16), 256, 0, stream>>>(xh, 1024, Wcat, bsum,
                                                     gates, NGATE, nullptr, NGATE, 1024);
        lstm_pw<false><<<2048, 256, 0, stream>>>(gates, cbuf, xh, packed);
        // logits = h @ W_out^T + b_out, fused argmax   N=11998 K=512
        gemm_nt<2><<<dim3(188, 16), 256, 0, stream>>>(xh + 512, 1024, W_out, b_out,
                                                      nullptr, 0, packed, NVOCAB, 512);
        finalize_step<<<4, 256, 0, stream>>>(packed, words, out, t);
    }
}

// Round 3
// 2820.242 us; speedup vs baseline: 1.5112x; 1.5112x over previous
//
#include <hip/hip_runtime.h>
#include <stdint.h>

#define BATCH  1024
#define SEQLEN 15
#define NGATE  2048
#define NVOCAB 11998
#define FEATS  4096

typedef __attribute__((ext_vector_type(8))) short  s8v;    // 8 bf16 bit-patterns (4 VGPRs)
typedef __attribute__((ext_vector_type(8))) unsigned short us8;
typedef __attribute__((ext_vector_type(4))) unsigned short us4;
typedef __attribute__((ext_vector_type(4))) float f32x4;

// bf16 round-to-nearest-even on bit patterns
__device__ __forceinline__ unsigned short f2bf(float f) {
    unsigned u = __float_as_uint(f);
    u += 0x7FFFu + ((u >> 16) & 1u);
    return (unsigned short)(u >> 16);
}
__device__ __forceinline__ float bf2f(unsigned short h) {
    return __uint_as_float(((unsigned)h) << 16);
}
struct bfpair { unsigned short hi, lo; };
__device__ __forceinline__ bfpair split2v(float v) {
    bfpair r;
    r.hi = f2bf(v);
    r.lo = f2bf(v - bf2f(r.hi));
    return r;
}

// ---------------------------------------------------------------------------
// prep: Wcat_hi/lo = split([W_ih | W_hh]) bf16, bsum = b_ih+b_hh, words = 1
// ---------------------------------------------------------------------------
__global__ void prep_kernel(const float* __restrict__ W_ih, const float* __restrict__ W_hh,
                            const float* __restrict__ b_ih, const float* __restrict__ b_hh,
                            unsigned short* __restrict__ Wcat_hi, unsigned short* __restrict__ Wcat_lo,
                            float* __restrict__ bsum, int* __restrict__ words) {
    int idx = blockIdx.x * 256 + threadIdx.x;
    if (idx < NGATE * 1024) {
        int n = idx >> 10, k = idx & 1023;
        float v = (k < 512) ? W_ih[n * 512 + k] : W_hh[n * 512 + (k - 512)];
        bfpair s = split2v(v);
        Wcat_hi[idx] = s.hi;
        Wcat_lo[idx] = s.lo;
    }
    if (idx < NGATE) bsum[idx] = b_ih[idx] + b_hh[idx];
    if (idx < BATCH) words[idx] = 1;
}

// ---------------------------------------------------------------------------
// fp32 tiled NT GEMM for the one-time image-feature layer (K=4096), epilogue
// relu + split-write into imgv_hi/lo. BM=BN=64, BK=16, 256 thr, 4x4 microtile.
// ---------------------------------------------------------------------------
__global__ __launch_bounds__(256) void gemm_feats(
    const float* __restrict__ A, const float* __restrict__ Bm,
    const float* __restrict__ bias,
    unsigned short* __restrict__ Chi, unsigned short* __restrict__ Clo)
{
    __shared__ __align__(16) float As[16][68];
    __shared__ __align__(16) float Bs[16][68];
    const int tid = threadIdx.x;
    const int bm = blockIdx.y * 64, bn = blockIdx.x * 64;
    const int tx = tid & 15, ty = tid >> 4;
    const int lrow = tid >> 2, lk4 = (tid & 3) << 2;

    float acc[4][4] = {};
    const float* Aptr = A + (size_t)(bm + lrow) * FEATS + lk4;
    const float* Bptr = Bm + (size_t)(bn + lrow) * FEATS + lk4;

    for (int k0 = 0; k0 < FEATS; k0 += 16) {
        float4 av = *(const float4*)(Aptr + k0);
        float4 bv = *(const float4*)(Bptr + k0);
        __syncthreads();
        As[lk4 + 0][lrow] = av.x;  As[lk4 + 1][lrow] = av.y;
        As[lk4 + 2][lrow] = av.z;  As[lk4 + 3][lrow] = av.w;
        Bs[lk4 + 0][lrow] = bv.x;  Bs[lk4 + 1][lrow] = bv.y;
        Bs[lk4 + 2][lrow] = bv.z;  Bs[lk4 + 3][lrow] = bv.w;
        __syncthreads();
        #pragma unroll
        for (int k = 0; k < 16; ++k) {
            float4 a4 = *(const float4*)(&As[k][ty << 2]);
            float4 b4 = *(const float4*)(&Bs[k][tx << 2]);
            float ar[4] = {a4.x, a4.y, a4.z, a4.w};
            float br[4] = {b4.x, b4.y, b4.z, b4.w};
            #pragma unroll
            for (int i = 0; i < 4; ++i)
                #pragma unroll
                for (int j = 0; j < 4; ++j)
                    acc[i][j] = fmaf(ar[i], br[j], acc[i][j]);
        }
    }
    #pragma unroll
    for (int i = 0; i < 4; ++i) {
        int m = bm + (ty << 2) + i;
        #pragma unroll
        for (int j = 0; j < 4; ++j) {
            int n = bn + (tx << 2) + j;
            float v = fmaxf(acc[i][j] + bias[n], 0.f);
            bfpair s = split2v(v);
            Chi[(size_t)m * 512 + n] = s.hi;
            Clo[(size_t)m * 512 + n] = s.lo;
        }
    }
}

// ---------------------------------------------------------------------------
// Split-bf16 MFMA NT GEMM: C[M,N] = A * W^T with fp32-grade accuracy via
// 3-product split (ah*bh + ah*bl + al*bh), 16x16x32 bf16 MFMA.
// 128x128 tile, 256 threads = 4 waves (2x2 of 64x64), 4x4 fragments/wave.
// BSPLIT=1: B pre-split bf16 (Bhi/Blo, ldb). BSPLIT=0: B fp32 (Bf, ldb),
//           split on the fly during staging.
// MODE 0: C = acc + bias (fp32 store).  MODE 2: fused bias+argmax -> packed.
// M multiple of 128; N guarded (tiles padded with zero rows).
// ---------------------------------------------------------------------------
template<int BSPLIT, int MODE>
__global__ __launch_bounds__(256) void mfma_gemm(
    const unsigned short* __restrict__ Ahi, const unsigned short* __restrict__ Alo, int lda,
    const unsigned short* __restrict__ Bhi, const unsigned short* __restrict__ Blo,
    const float* __restrict__ Bf, int ldb,
    const float* __restrict__ bias,
    float* __restrict__ C, int ldc,
    unsigned long long* __restrict__ packed,
    int N, int K)
{
    // 4 tiles of 128 rows x 32 k, row stride 40 shorts (80 B: 16B-aligned,
    // <=2-way bank aliasing on ds_read_b128 = free per m136)
    __shared__ short smem[4 * 128 * 40];
    short* sAhi = smem;
    short* sAlo = smem + 128 * 40;
    short* sBhi = smem + 2 * 128 * 40;
    short* sBlo = smem + 3 * 128 * 40;

    const int tid  = threadIdx.x;
    const int lane = tid & 63, wave = tid >> 6;
    const int wr = (wave & 1) * 64, wc = (wave >> 1) * 64;
    const int frow = lane & 15, quad = lane >> 4;
    const int bm = blockIdx.y * 128, bn = blockIdx.x * 128;

    f32x4 acc[4][4] = {};

    for (int k0 = 0; k0 < K; k0 += 32) {
        __syncthreads();
        // ---- stage A (pre-split bf16): 2 passes x (hi+lo)
        #pragma unroll
        for (int p = 0; p < 2; ++p) {
            int flat = p * 256 + tid;            // 0..511
            int row = flat >> 2;                 // 0..127
            int c8  = (flat & 3) << 3;           // 0,8,16,24
            size_t g = (size_t)(bm + row) * lda + k0 + c8;
            *(us8*)(sAhi + row * 40 + c8) = *(const us8*)(Ahi + g);
            *(us8*)(sAlo + row * 40 + c8) = *(const us8*)(Alo + g);
        }
        // ---- stage B
        if (BSPLIT) {
            #pragma unroll
            for (int p = 0; p < 2; ++p) {
                int flat = p * 256 + tid;
                int row = flat >> 2;
                int c8  = (flat & 3) << 3;
                int nrow = bn + row;
                us8 vh = (us8)0, vl = (us8)0;
                if (nrow < N) {
                    size_t g = (size_t)nrow * ldb + k0 + c8;
                    vh = *(const us8*)(Bhi + g);
                    vl = *(const us8*)(Blo + g);
                }
                *(us8*)(sBhi + row * 40 + c8) = vh;
                *(us8*)(sBlo + row * 40 + c8) = vl;
            }
        } else {
            #pragma unroll
            for (int p = 0; p < 4; ++p) {
                int flat = p * 256 + tid;        // 0..1023
                int row = flat >> 3;             // 0..127
                int c4  = (flat & 7) << 2;       // 0,4,..,28
                int nrow = bn + row;
                float4 f = make_float4(0.f, 0.f, 0.f, 0.f);
                if (nrow < N) f = *(const float4*)(Bf + (size_t)nrow * ldb + k0 + c4);
                bfpair sx = split2v(f.x), sy = split2v(f.y);
                bfpair sz = split2v(f.z), sw = split2v(f.w);
                us4 vh, vl;
                vh.x = sx.hi; vl.x = sx.lo;
                vh.y = sy.hi; vl.y = sy.lo;
                vh.z = sz.hi; vl.z = sz.lo;
                vh.w = sw.hi; vl.w = sw.lo;
                *(us4*)(sBhi + row * 40 + c4) = vh;
                *(us4*)(sBlo + row * 40 + c4) = vl;
            }
        }
        __syncthreads();

        // ---- fragments: lane holds op[row=frow][k=quad*8+j]
        s8v ah[4], al[4], bh[4], bl[4];
        #pragma unroll
        for (int i = 0; i < 4; ++i) {
            int r = wr + i * 16 + frow;
            ah[i] = *(const s8v*)(sAhi + r * 40 + quad * 8);
            al[i] = *(const s8v*)(sAlo + r * 40 + quad * 8);
        }
        #pragma unroll
        for (int j = 0; j < 4; ++j) {
            int r = wc + j * 16 + frow;
            bh[j] = *(const s8v*)(sBhi + r * 40 + quad * 8);
            bl[j] = *(const s8v*)(sBlo + r * 40 + quad * 8);
        }
        #pragma unroll
        for (int i = 0; i < 4; ++i)
            #pragma unroll
            for (int j = 0; j < 4; ++j) {
                acc[i][j] = __builtin_amdgcn_mfma_f32_16x16x32_bf16(ah[i], bh[j], acc[i][j], 0, 0, 0);
                acc[i][j] = __builtin_amdgcn_mfma_f32_16x16x32_bf16(ah[i], bl[j], acc[i][j], 0, 0, 0);
                acc[i][j] = __builtin_amdgcn_mfma_f32_16x16x32_bf16(al[i], bh[j], acc[i][j], 0, 0, 0);
            }
    }

    // C/D layout: col = lane&15, row = quad*4 + reg  (m89-verified)
    if (MODE == 0) {
        #pragma unroll
        for (int i = 0; i < 4; ++i)
            #pragma unroll
            for (int r = 0; r < 4; ++r) {
                int m = bm + wr + i * 16 + quad * 4 + r;
                #pragma unroll
                for (int j = 0; j < 4; ++j) {
                    int n = bn + wc + j * 16 + frow;
                    if (n < N) C[(size_t)m * ldc + n] = acc[i][j][r] + bias[n];
                }
            }
    } else {
        #pragma unroll
        for (int i = 0; i < 4; ++i)
            #pragma unroll
            for (int r = 0; r < 4; ++r) {
                int m = bm + wr + i * 16 + quad * 4 + r;
                unsigned long long best = 0ull;
                #pragma unroll
                for (int j = 0; j < 4; ++j) {
                    int n = bn + wc + j * 16 + frow;
                    if (n < N) {
                        float v = acc[i][j][r] + bias[n];
                        unsigned int u   = __float_as_uint(v);
                        unsigned int key = (u & 0x80000000u) ? ~u : (u | 0x80000000u);
                        unsigned long long p =
                            ((unsigned long long)key << 32) |
                            (unsigned long long)(0xFFFFFFFFu - (unsigned)n);
                        best = (p > best) ? p : best;
                    }
                }
                // reduce over the 16 lanes of this quad (they hold this row's cols)
                #pragma unroll
                for (int s = 1; s < 16; s <<= 1) {
                    unsigned long long o = __shfl_xor(best, s, 64);
                    best = (o > best) ? o : best;
                }
                if (frow == 0) atomicMax(&packed[m], best);
            }
    }
}

// ---------------------------------------------------------------------------
// LSTM pointwise: gates[B,2048] -> c; h split-written to xh_hi/lo[:,512:1024];
// zeroes packed[] for the next argmax.
// ---------------------------------------------------------------------------
template<bool PRIME>
__global__ void lstm_pw(const float* __restrict__ gates, float* __restrict__ cbuf,
                        unsigned short* __restrict__ xh_hi, unsigned short* __restrict__ xh_lo,
                        unsigned long long* __restrict__ packed) {
    int idx = blockIdx.x * 256 + threadIdx.x;  // over 1024*512
    int b = idx >> 9, j = idx & 511;
    const float* g = gates + (size_t)b * NGATE;
    float gi = g[j], gf = g[512 + j], gg = g[1024 + j], go = g[1536 + j];
    float si = 1.f / (1.f + expf(-gi));
    float sf = 1.f / (1.f + expf(-gf));
    float so = 1.f / (1.f + expf(-go));
    float tg = tanhf(gg);
    float cn = PRIME ? (si * tg) : (sf * cbuf[idx] + si * tg);
    cbuf[idx] = cn;
    float h = so * tanhf(cn);
    bfpair s = split2v(h);
    xh_hi[(size_t)b * 1024 + 512 + j] = s.hi;
    xh_lo[(size_t)b * 1024 + 512 + j] = s.lo;
    if (j == 0) packed[b] = 0ull;
}

// ---------------------------------------------------------------------------
// embedding gather + split into xh_hi/lo[:,0:512]
// ---------------------------------------------------------------------------
__global__ void gather_emb(const float* __restrict__ emb, const int* __restrict__ words,
                           unsigned short* __restrict__ xh_hi, unsigned short* __restrict__ xh_lo) {
    int idx = blockIdx.x * 256 + threadIdx.x;   // 1024*128
    int b = idx >> 7, j4 = (idx & 127) << 2;
    float4 v = *(const float4*)(emb + (size_t)words[b] * 512 + j4);
    bfpair sx = split2v(v.x), sy = split2v(v.y);
    bfpair sz = split2v(v.z), sw = split2v(v.w);
    us4 vh, vl;
    vh.x = sx.hi; vl.x = sx.lo;
    vh.y = sy.hi; vl.y = sy.lo;
    vh.z = sz.hi; vl.z = sz.lo;
    vh.w = sw.hi; vl.w = sw.lo;
    *(us4*)(xh_hi + (size_t)b * 1024 + j4) = vh;
    *(us4*)(xh_lo + (size_t)b * 1024 + j4) = vl;
}

// ---------------------------------------------------------------------------
// finalize one step: unpack argmax, emit token, set next word id
// ---------------------------------------------------------------------------
__global__ void finalize_step(const unsigned long long* __restrict__ packed,
                              int* __restrict__ words, int* __restrict__ out, int t) {
    int b = blockIdx.x * 256 + threadIdx.x;
    if (b < BATCH) {
        unsigned long long p = packed[b];
        int idx = (int)(0xFFFFFFFFu - (unsigned)(p & 0xFFFFFFFFull));
        out[b * SEQLEN + t] = idx;
        words[b] = idx + 2;
    }
}

extern "C" void kernel_launch(void* const* d_in, const int* in_sizes, int n_in,
                              void* d_out, int out_size, void* d_ws, size_t ws_size,
                              hipStream_t stream) {
    const float* img     = (const float*)d_in[0];
    const float* W_feats = (const float*)d_in[1];
    const float* b_feats = (const float*)d_in[2];
    const float* W_ih    = (const float*)d_in[3];
    const float* W_hh    = (const float*)d_in[4];
    const float* b_ih    = (const float*)d_in[5];
    const float* b_hh    = (const float*)d_in[6];
    const float* emb     = (const float*)d_in[7];
    const float* W_out   = (const float*)d_in[8];
    const float* b_out   = (const float*)d_in[9];
    int* out = (int*)d_out;

    // workspace layout (~24 MB)
    char* p = (char*)d_ws;
    unsigned short* Wcat_hi = (unsigned short*)p;           p += (size_t)NGATE * 1024 * 2;
    unsigned short* Wcat_lo = (unsigned short*)p;           p += (size_t)NGATE * 1024 * 2;
    unsigned short* imgv_hi = (unsigned short*)p;           p += (size_t)1024 * 512 * 2;
    unsigned short* imgv_lo = (unsigned short*)p;           p += (size_t)1024 * 512 * 2;
    unsigned short* xh_hi   = (unsigned short*)p;           p += (size_t)1024 * 1024 * 2;
    unsigned short* xh_lo   = (unsigned short*)p;           p += (size_t)1024 * 1024 * 2;
    float* gates            = (float*)p;                    p += (size_t)1024 * NGATE * 4;
    float* cbuf             = (float*)p;                    p += (size_t)1024 * 512 * 4;
    float* bsum             = (float*)p;                    p += (size_t)NGATE * 4;
    unsigned long long* packed = (unsigned long long*)p;    p += (size_t)1024 * 8;
    int* words              = (int*)p;

    prep_kernel<<<8192, 256, 0, stream>>>(W_ih, W_hh, b_ih, b_hh, Wcat_hi, Wcat_lo, bsum, words);

    // imgv = split(relu(img @ W_feats^T + b_feats))   M=1024 N=512 K=4096
    gemm_feats<<<dim3(8, 16), 256, 0, stream>>>(img, W_feats, b_feats, imgv_hi, imgv_lo);

    // prime LSTM: gates = imgv @ W_ih^T + bsum   (W_ih = Wcat cols 0..511)
    mfma_gemm<1, 0><<<dim3(16, 8), 256, 0, stream>>>(
        imgv_hi, imgv_lo, 512, Wcat_hi, Wcat_lo, nullptr, 1024,
        bsum, gates, NGATE, nullptr, NGATE, 512);
    lstm_pw<true><<<2048, 256, 0, stream>>>(gates, cbuf, xh_hi, xh_lo, packed);

    for (int t = 0; t < SEQLEN; ++t) {
        gather_emb<<<512, 256, 0, stream>>>(emb, words, xh_hi, xh_lo);
        // gates = [x|h] @ [W_ih|W_hh]^T + bsum   N=2048 K=1024
        mfma_gemm<1, 0><<<dim3(16, 8), 256, 0, stream>>>(
            xh_hi, xh_lo, 1024, Wcat_hi, Wcat_lo, nullptr, 1024,
            bsum, gates, NGATE, nullptr, NGATE, 1024);
        lstm_pw<false><<<2048, 256, 0, stream>>>(gates, cbuf, xh_hi, xh_lo, packed);
        // logits = h @ W_out^T + b_out, fused argmax   N=11998 K=512 (B split on the fly)
        mfma_gemm<0, 2><<<dim3(94, 8), 256, 0, stream>>>(
            xh_hi + 512, xh_lo + 512, 1024, nullptr, nullptr, W_out, 512,
            b_out, nullptr, 0, packed, NVOCAB, 512);
        finalize_step<<<4, 256, 0, stream>>>(packed, words, out, t);
    }
}

// Round 4
// 2061.325 us; speedup vs baseline: 2.0676x; 1.3682x over previous
//
#include <hip/hip_runtime.h>
#include <stdint.h>

#define BATCH  1024
#define SEQLEN 15
#define NGATE  2048
#define NVOCAB 11998
#define FEATS  4096

typedef __attribute__((ext_vector_type(8))) short  s8v;    // 8 bf16 bit-patterns (4 VGPRs)
typedef __attribute__((ext_vector_type(8))) unsigned short us8;
typedef __attribute__((ext_vector_type(4))) unsigned short us4;
typedef __attribute__((ext_vector_type(4))) float f32x4;

// bf16 round-to-nearest-even on bit patterns
__device__ __forceinline__ unsigned short f2bf(float f) {
    unsigned u = __float_as_uint(f);
    u += 0x7FFFu + ((u >> 16) & 1u);
    return (unsigned short)(u >> 16);
}
__device__ __forceinline__ float bf2f(unsigned short h) {
    return __uint_as_float(((unsigned)h) << 16);
}
struct bfpair { unsigned short hi, lo; };
__device__ __forceinline__ bfpair split2v(float v) {
    bfpair r;
    r.hi = f2bf(v);
    r.lo = f2bf(v - bf2f(r.hi));
    return r;
}

// ---------------------------------------------------------------------------
// prep: Wcat_hi/lo = split([W_ih | W_hh]) bf16, bsum = b_ih + b_hh
// ---------------------------------------------------------------------------
__global__ void prep_kernel(const float* __restrict__ W_ih, const float* __restrict__ W_hh,
                            const float* __restrict__ b_ih, const float* __restrict__ b_hh,
                            unsigned short* __restrict__ Wcat_hi, unsigned short* __restrict__ Wcat_lo,
                            float* __restrict__ bsum) {
    int idx = blockIdx.x * 256 + threadIdx.x;
    if (idx < NGATE * 1024) {
        int n = idx >> 10, k = idx & 1023;
        float v = (k < 512) ? W_ih[n * 512 + k] : W_hh[n * 512 + (k - 512)];
        bfpair s = split2v(v);
        Wcat_hi[idx] = s.hi;
        Wcat_lo[idx] = s.lo;
    }
    if (idx < NGATE) bsum[idx] = b_ih[idx] + b_hh[idx];
}

// ---------------------------------------------------------------------------
// generic fp32 -> bf16 hi/lo split (float4 vectorized), n % 4 == 0
// ---------------------------------------------------------------------------
__global__ void split_f4(const float* __restrict__ src,
                         unsigned short* __restrict__ hi, unsigned short* __restrict__ lo,
                         int n4) {
    int i = blockIdx.x * 256 + threadIdx.x;
    if (i >= n4) return;
    float4 v = *(const float4*)(src + (size_t)i * 4);
    bfpair sx = split2v(v.x), sy = split2v(v.y), sz = split2v(v.z), sw = split2v(v.w);
    us4 vh, vl;
    vh.x = sx.hi; vl.x = sx.lo;  vh.y = sy.hi; vl.y = sy.lo;
    vh.z = sz.hi; vl.z = sz.lo;  vh.w = sw.hi; vl.w = sw.lo;
    *(us4*)(hi + (size_t)i * 4) = vh;
    *(us4*)(lo + (size_t)i * 4) = vl;
}

// ---------------------------------------------------------------------------
// Split-bf16 MFMA NT GEMM: C[M,N] = A * B^T, 3-product bf16x3 split,
// 16x16x32 MFMA, 128x128 tile, 256 threads = 4 waves, 4x4 frags/wave.
// ASPLIT/BSPLIT: operand pre-split bf16 (1) or fp32 split on the fly (0).
// MODE 2: fused bias + per-row argmax -> packed (u64 atomicMax).
// MODE 3: raw fp32 store of acc (no bias).
// blockIdx.z = split-K chunk: operands advance z*kstride columns; C advances
// z*czstride elements (MODE 3). M multiple of 128; N guarded.
// ---------------------------------------------------------------------------
template<int ASPLIT, int BSPLIT, int MODE>
__global__ __launch_bounds__(256) void mfma_gemm(
    const unsigned short* __restrict__ Ahi, const unsigned short* __restrict__ Alo,
    const float* __restrict__ Af, int lda,
    const unsigned short* __restrict__ Bhi, const unsigned short* __restrict__ Blo,
    const float* __restrict__ Bf, int ldb,
    const float* __restrict__ bias,
    float* __restrict__ C, int ldc,
    unsigned long long* __restrict__ packed,
    int N, int K, int kstride, size_t czstride)
{
    __shared__ short smem[4 * 128 * 40];   // stride 40 shorts: 2-way bank alias = free
    short* sAhi = smem;
    short* sAlo = smem + 128 * 40;
    short* sBhi = smem + 2 * 128 * 40;
    short* sBlo = smem + 3 * 128 * 40;

    const int kz = blockIdx.z;
    if (ASPLIT) { Ahi += (size_t)kz * kstride; Alo += (size_t)kz * kstride; }
    else        { Af  += (size_t)kz * kstride; }
    if (BSPLIT) { Bhi += (size_t)kz * kstride; Blo += (size_t)kz * kstride; }
    else        { Bf  += (size_t)kz * kstride; }
    if (MODE == 3) C += (size_t)kz * czstride;

    const int tid  = threadIdx.x;
    const int lane = tid & 63, wave = tid >> 6;
    const int wr = (wave & 1) * 64, wc = (wave >> 1) * 64;
    const int frow = lane & 15, quad = lane >> 4;
    const int bm = blockIdx.y * 128, bn = blockIdx.x * 128;

    f32x4 acc[4][4] = {};

    for (int k0 = 0; k0 < K; k0 += 32) {
        __syncthreads();
        // ---- stage A
        if (ASPLIT) {
            #pragma unroll
            for (int p = 0; p < 2; ++p) {
                int flat = p * 256 + tid;
                int row = flat >> 2;
                int c8  = (flat & 3) << 3;
                size_t g = (size_t)(bm + row) * lda + k0 + c8;
                *(us8*)(sAhi + row * 40 + c8) = *(const us8*)(Ahi + g);
                *(us8*)(sAlo + row * 40 + c8) = *(const us8*)(Alo + g);
            }
        } else {
            #pragma unroll
            for (int p = 0; p < 4; ++p) {
                int flat = p * 256 + tid;
                int row = flat >> 3;
                int c4  = (flat & 7) << 2;
                float4 f = *(const float4*)(Af + (size_t)(bm + row) * lda + k0 + c4);
                bfpair sx = split2v(f.x), sy = split2v(f.y), sz = split2v(f.z), sw = split2v(f.w);
                us4 vh, vl;
                vh.x = sx.hi; vl.x = sx.lo;  vh.y = sy.hi; vl.y = sy.lo;
                vh.z = sz.hi; vl.z = sz.lo;  vh.w = sw.hi; vl.w = sw.lo;
                *(us4*)(sAhi + row * 40 + c4) = vh;
                *(us4*)(sAlo + row * 40 + c4) = vl;
            }
        }
        // ---- stage B
        if (BSPLIT) {
            #pragma unroll
            for (int p = 0; p < 2; ++p) {
                int flat = p * 256 + tid;
                int row = flat >> 2;
                int c8  = (flat & 3) << 3;
                int nrow = bn + row;
                us8 vh = (us8)0, vl = (us8)0;
                if (nrow < N) {
                    size_t g = (size_t)nrow * ldb + k0 + c8;
                    vh = *(const us8*)(Bhi + g);
                    vl = *(const us8*)(Blo + g);
                }
                *(us8*)(sBhi + row * 40 + c8) = vh;
                *(us8*)(sBlo + row * 40 + c8) = vl;
            }
        } else {
            #pragma unroll
            for (int p = 0; p < 4; ++p) {
                int flat = p * 256 + tid;
                int row = flat >> 3;
                int c4  = (flat & 7) << 2;
                int nrow = bn + row;
                float4 f = make_float4(0.f, 0.f, 0.f, 0.f);
                if (nrow < N) f = *(const float4*)(Bf + (size_t)nrow * ldb + k0 + c4);
                bfpair sx = split2v(f.x), sy = split2v(f.y), sz = split2v(f.z), sw = split2v(f.w);
                us4 vh, vl;
                vh.x = sx.hi; vl.x = sx.lo;  vh.y = sy.hi; vl.y = sy.lo;
                vh.z = sz.hi; vl.z = sz.lo;  vh.w = sw.hi; vl.w = sw.lo;
                *(us4*)(sBhi + row * 40 + c4) = vh;
                *(us4*)(sBlo + row * 40 + c4) = vl;
            }
        }
        __syncthreads();

        s8v ah[4], al[4], bh[4], bl[4];
        #pragma unroll
        for (int i = 0; i < 4; ++i) {
            int r = wr + i * 16 + frow;
            ah[i] = *(const s8v*)(sAhi + r * 40 + quad * 8);
            al[i] = *(const s8v*)(sAlo + r * 40 + quad * 8);
        }
        #pragma unroll
        for (int j = 0; j < 4; ++j) {
            int r = wc + j * 16 + frow;
            bh[j] = *(const s8v*)(sBhi + r * 40 + quad * 8);
            bl[j] = *(const s8v*)(sBlo + r * 40 + quad * 8);
        }
        #pragma unroll
        for (int i = 0; i < 4; ++i)
            #pragma unroll
            for (int j = 0; j < 4; ++j) {
                acc[i][j] = __builtin_amdgcn_mfma_f32_16x16x32_bf16(ah[i], bh[j], acc[i][j], 0, 0, 0);
                acc[i][j] = __builtin_amdgcn_mfma_f32_16x16x32_bf16(ah[i], bl[j], acc[i][j], 0, 0, 0);
                acc[i][j] = __builtin_amdgcn_mfma_f32_16x16x32_bf16(al[i], bh[j], acc[i][j], 0, 0, 0);
            }
    }

    // C/D layout: col = lane&15, row = quad*4 + reg  (m89-verified)
    if (MODE == 3) {
        #pragma unroll
        for (int i = 0; i < 4; ++i)
            #pragma unroll
            for (int r = 0; r < 4; ++r) {
                int m = bm + wr + i * 16 + quad * 4 + r;
                #pragma unroll
                for (int j = 0; j < 4; ++j) {
                    int n = bn + wc + j * 16 + frow;
                    if (n < N) C[(size_t)m * ldc + n] = acc[i][j][r];
                }
            }
    } else {
        #pragma unroll
        for (int i = 0; i < 4; ++i)
            #pragma unroll
            for (int r = 0; r < 4; ++r) {
                int m = bm + wr + i * 16 + quad * 4 + r;
                unsigned long long best = 0ull;
                #pragma unroll
                for (int j = 0; j < 4; ++j) {
                    int n = bn + wc + j * 16 + frow;
                    if (n < N) {
                        float v = acc[i][j][r] + bias[n];
                        unsigned int u   = __float_as_uint(v);
                        unsigned int key = (u & 0x80000000u) ? ~u : (u | 0x80000000u);
                        unsigned long long p =
                            ((unsigned long long)key << 32) |
                            (unsigned long long)(0xFFFFFFFFu - (unsigned)n);
                        best = (p > best) ? p : best;
                    }
                }
                #pragma unroll
                for (int s = 1; s < 16; s <<= 1) {
                    unsigned long long o = __shfl_xor(best, s, 64);
                    best = (o > best) ? o : best;
                }
                if (frow == 0) atomicMax(&packed[m], best);
            }
    }
}

// ---------------------------------------------------------------------------
// feats reduce: sum 4 split-K partials + bias, relu, split -> imgv hi/lo
// ---------------------------------------------------------------------------
__global__ void feats_reduce(const float* __restrict__ part, const float* __restrict__ bias,
                             unsigned short* __restrict__ Chi, unsigned short* __restrict__ Clo) {
    int i = blockIdx.x * 256 + threadIdx.x;        // over 1024*512/4
    size_t i4 = (size_t)i * 4;
    int n = (int)(i4 & 511);
    const size_t S = (size_t)1024 * 512;
    float4 a = *(const float4*)(part + i4);
    float4 b = *(const float4*)(part + i4 + S);
    float4 c = *(const float4*)(part + i4 + 2 * S);
    float4 d = *(const float4*)(part + i4 + 3 * S);
    float4 bs = *(const float4*)(bias + n);
    float vx = fmaxf(a.x + b.x + c.x + d.x + bs.x, 0.f);
    float vy = fmaxf(a.y + b.y + c.y + d.y + bs.y, 0.f);
    float vz = fmaxf(a.z + b.z + c.z + d.z + bs.z, 0.f);
    float vw = fmaxf(a.w + b.w + c.w + d.w + bs.w, 0.f);
    bfpair sx = split2v(vx), sy = split2v(vy), sz = split2v(vz), sw = split2v(vw);
    us4 vh, vl;
    vh.x = sx.hi; vl.x = sx.lo;  vh.y = sy.hi; vl.y = sy.lo;
    vh.z = sz.hi; vl.z = sz.lo;  vh.w = sw.hi; vl.w = sw.lo;
    *(us4*)(Chi + i4) = vh;
    *(us4*)(Clo + i4) = vl;
}

// ---------------------------------------------------------------------------
// LSTM pointwise: gates (raw, optionally two split-K partials) + bsum -> c, h
// h split-written to xh[:,512:1024]; zeroes packed[] for the next argmax.
// ---------------------------------------------------------------------------
template<bool PRIME>
__global__ void lstm_pw(const float* __restrict__ g0, const float* __restrict__ g1,
                        const float* __restrict__ bsum, float* __restrict__ cbuf,
                        unsigned short* __restrict__ xh_hi, unsigned short* __restrict__ xh_lo,
                        unsigned long long* __restrict__ packed) {
    int idx = blockIdx.x * 256 + threadIdx.x;  // over 1024*512
    int b = idx >> 9, j = idx & 511;
    const float* g = g0 + (size_t)b * NGATE;
    float gi = g[j]        + bsum[j];
    float gf = g[512 + j]  + bsum[512 + j];
    float gg = g[1024 + j] + bsum[1024 + j];
    float go = g[1536 + j] + bsum[1536 + j];
    if (g1) {
        const float* h = g1 + (size_t)b * NGATE;
        gi += h[j]; gf += h[512 + j]; gg += h[1024 + j]; go += h[1536 + j];
    }
    float si = 1.f / (1.f + expf(-gi));
    float sf = 1.f / (1.f + expf(-gf));
    float so = 1.f / (1.f + expf(-go));
    float tg = tanhf(gg);
    float cn = PRIME ? (si * tg) : (sf * cbuf[idx] + si * tg);
    cbuf[idx] = cn;
    float h = so * tanhf(cn);
    bfpair s = split2v(h);
    xh_hi[(size_t)b * 1024 + 512 + j] = s.hi;
    xh_lo[(size_t)b * 1024 + 512 + j] = s.lo;
    if (j == 0) packed[b] = 0ull;
}

// ---------------------------------------------------------------------------
// fused finalize(t-1) + embedding gather + split into xh[:,0:512]
// FIRST: word = START(1). Else: unpack packed -> out[b][t-1], word = id+2.
// ---------------------------------------------------------------------------
template<int FIRST>
__global__ void gather_fused(const float* __restrict__ emb,
                             const unsigned long long* __restrict__ packed,
                             unsigned short* __restrict__ xh_hi, unsigned short* __restrict__ xh_lo,
                             int* __restrict__ out, int t) {
    int idx = blockIdx.x * 256 + threadIdx.x;   // 1024*128
    int b = idx >> 7, j4 = (idx & 127) << 2;
    int word;
    if (FIRST) {
        word = 1;
    } else {
        unsigned long long p = packed[b];
        int id = (int)(0xFFFFFFFFu - (unsigned)(p & 0xFFFFFFFFull));
        word = id + 2;
        if ((idx & 127) == 0) out[b * SEQLEN + (t - 1)] = id;
    }
    float4 v = *(const float4*)(emb + (size_t)word * 512 + j4);
    bfpair sx = split2v(v.x), sy = split2v(v.y), sz = split2v(v.z), sw = split2v(v.w);
    us4 vh, vl;
    vh.x = sx.hi; vl.x = sx.lo;  vh.y = sy.hi; vl.y = sy.lo;
    vh.z = sz.hi; vl.z = sz.lo;  vh.w = sw.hi; vl.w = sw.lo;
    *(us4*)(xh_hi + (size_t)b * 1024 + j4) = vh;
    *(us4*)(xh_lo + (size_t)b * 1024 + j4) = vl;
}

__global__ void final_out(const unsigned long long* __restrict__ packed, int* __restrict__ out) {
    int b = blockIdx.x * 256 + threadIdx.x;
    if (b < BATCH) {
        unsigned long long p = packed[b];
        out[b * SEQLEN + (SEQLEN - 1)] = (int)(0xFFFFFFFFu - (unsigned)(p & 0xFFFFFFFFull));
    }
}

extern "C" void kernel_launch(void* const* d_in, const int* in_sizes, int n_in,
                              void* d_out, int out_size, void* d_ws, size_t ws_size,
                              hipStream_t stream) {
    const float* img     = (const float*)d_in[0];
    const float* W_feats = (const float*)d_in[1];
    const float* b_feats = (const float*)d_in[2];
    const float* W_ih    = (const float*)d_in[3];
    const float* W_hh    = (const float*)d_in[4];
    const float* b_ih    = (const float*)d_in[5];
    const float* b_hh    = (const float*)d_in[6];
    const float* emb     = (const float*)d_in[7];
    const float* W_out   = (const float*)d_in[8];
    const float* b_out   = (const float*)d_in[9];
    int* out = (int*)d_out;

    // ---- workspace layout (common prefix = 25.18 MB; BIG adds 32.96 MB)
    char* p = (char*)d_ws;
    unsigned short* Wcat_hi = (unsigned short*)p;  p += (size_t)NGATE * 1024 * 2;
    unsigned short* Wcat_lo = (unsigned short*)p;  p += (size_t)NGATE * 1024 * 2;
    unsigned short* xh_hi   = (unsigned short*)p;  p += (size_t)1024 * 1024 * 2;
    unsigned short* xh_lo   = (unsigned short*)p;  p += (size_t)1024 * 1024 * 2;
    unsigned short* imgv_hi = (unsigned short*)p;  p += (size_t)1024 * 512 * 2;
    unsigned short* imgv_lo = (unsigned short*)p;  p += (size_t)1024 * 512 * 2;
    float* cbuf             = (float*)p;           p += (size_t)1024 * 512 * 4;
    float* bsum             = (float*)p;           p += (size_t)NGATE * 4;
    unsigned long long* packed = (unsigned long long*)p;  p += (size_t)1024 * 8;
    float* gates0           = (float*)p;           p += (size_t)1024 * NGATE * 4;
    // BIG extras:
    float* gates1           = (float*)p;           p += (size_t)1024 * NGATE * 4;
    unsigned short* Wout_hi = (unsigned short*)p;  p += (size_t)NVOCAB * 512 * 2;
    unsigned short* Wout_lo = (unsigned short*)p;  p += (size_t)NVOCAB * 512 * 2;
    const size_t need_big = (size_t)(p - (char*)d_ws);
    const bool big = (ws_size >= need_big);
    float* partials = gates0;   // 4 x 1024x512 fp32 = 8.39 MB, aliases gates0 exactly

    prep_kernel<<<8192, 256, 0, stream>>>(W_ih, W_hh, b_ih, b_hh, Wcat_hi, Wcat_lo, bsum);
    if (big) {
        split_f4<<<(NVOCAB * 512 / 4 + 255) / 256, 256, 0, stream>>>(W_out, Wout_hi, Wout_lo, NVOCAB * 512 / 4);
    }

    // feats: partials[z] = img(K-chunk z) @ W_feats(chunk z)^T ; split-K x4
    mfma_gemm<0, 0, 3><<<dim3(4, 8, 4), 256, 0, stream>>>(
        nullptr, nullptr, img, FEATS, nullptr, nullptr, W_feats, FEATS,
        nullptr, partials, 512, nullptr, 512, 1024, 1024, (size_t)1024 * 512);
    feats_reduce<<<512, 256, 0, stream>>>(partials, b_feats, imgv_hi, imgv_lo);

    // prime LSTM: gates0 = imgv @ W_ih^T (raw)
    mfma_gemm<1, 1, 3><<<dim3(16, 8, 1), 256, 0, stream>>>(
        imgv_hi, imgv_lo, nullptr, 512, Wcat_hi, Wcat_lo, nullptr, 1024,
        nullptr, gates0, NGATE, nullptr, NGATE, 512, 0, 0);
    lstm_pw<true><<<2048, 256, 0, stream>>>(gates0, nullptr, bsum, cbuf, xh_hi, xh_lo, packed);

    for (int t = 0; t < SEQLEN; ++t) {
        if (t == 0) gather_fused<1><<<512, 256, 0, stream>>>(emb, packed, xh_hi, xh_lo, out, t);
        else        gather_fused<0><<<512, 256, 0, stream>>>(emb, packed, xh_hi, xh_lo, out, t);

        if (big) {
            // gates{0,1} = xh(chunk z) @ Wcat(chunk z)^T ; split-K x2, 256 blocks
            mfma_gemm<1, 1, 3><<<dim3(16, 8, 2), 256, 0, stream>>>(
                xh_hi, xh_lo, nullptr, 1024, Wcat_hi, Wcat_lo, nullptr, 1024,
                nullptr, gates0, NGATE, nullptr, NGATE, 512, 512, (size_t)NGATE * 1024);
            lstm_pw<false><<<2048, 256, 0, stream>>>(gates0, gates1, bsum, cbuf, xh_hi, xh_lo, packed);
            mfma_gemm<1, 1, 2><<<dim3(94, 8, 1), 256, 0, stream>>>(
                xh_hi + 512, xh_lo + 512, nullptr, 1024, Wout_hi, Wout_lo, nullptr, 512,
                b_out, nullptr, 0, packed, NVOCAB, 512, 0, 0);
        } else {
            mfma_gemm<1, 1, 3><<<dim3(16, 8, 1), 256, 0, stream>>>(
                xh_hi, xh_lo, nullptr, 1024, Wcat_hi, Wcat_lo, nullptr, 1024,
                nullptr, gates0, NGATE, nullptr, NGATE, 1024, 0, 0);
            lstm_pw<false><<<2048, 256, 0, stream>>>(gates0, nullptr, bsum, cbuf, xh_hi, xh_lo, packed);
            mfma_gemm<1, 0, 2><<<dim3(94, 8, 1), 256, 0, stream>>>(
                xh_hi + 512, xh_lo + 512, nullptr, 1024, nullptr, nullptr, W_out, 512,
                b_out, nullptr, 0, packed, NVOCAB, 512, 0, 0);
        }
    }
    final_out<<<4, 256, 0, stream>>>(packed, out);
}

// Round 5
// 1844.564 us; speedup vs baseline: 2.3105x; 1.1175x over previous
//
#include <hip/hip_runtime.h>
#include <stdint.h>

#define BATCH  1024
#define SEQLEN 15
#define NGATE  2048
#define NVOCAB 11998
#define FEATS  4096

typedef __attribute__((ext_vector_type(8)))  short  s8v;     // 8 bf16 bit patterns
typedef __attribute__((ext_vector_type(16))) float  f32x16;  // 32x32 MFMA acc
typedef __attribute__((ext_vector_type(8)))  unsigned short us8;

// bf16 round-to-nearest-even on bit patterns
__device__ __forceinline__ unsigned short f2bf(float f) {
    unsigned u = __float_as_uint(f);
    u += 0x7FFFu + ((u >> 16) & 1u);
    return (unsigned short)(u >> 16);
}
__device__ __forceinline__ float bf2f(unsigned short h) {
    return __uint_as_float(((unsigned)h) << 16);
}
struct bfpair { unsigned short hi, lo; };
__device__ __forceinline__ bfpair split2v(float v) {
    bfpair r;
    r.hi = f2bf(v);
    r.lo = f2bf(v - bf2f(r.hi));
    return r;
}
// split 8 consecutive floats -> two us8
__device__ __forceinline__ void split8(const float* __restrict__ s, us8& vh, us8& vl) {
    #pragma unroll
    for (int e = 0; e < 8; ++e) {
        bfpair q = split2v(s[e]);
        vh[e] = q.hi; vl[e] = q.lo;
    }
}

// async 16B-per-lane global->LDS (LDS dest = wave-uniform base + lane*16)
__device__ __forceinline__ void async_cp16(const void* g, void* l) {
    __builtin_amdgcn_global_load_lds(
        (const __attribute__((address_space(1))) unsigned int*)g,
        (__attribute__((address_space(3))) unsigned int*)l, 16, 0, 0);
}

// ---------------------------------------------------------------------------
// prep: Wcat blocked [128 kc][2048 row][8] = split([W_ih | W_hh]); bsum
// ---------------------------------------------------------------------------
__global__ void prep_wcat_blk(const float* __restrict__ W_ih, const float* __restrict__ W_hh,
                              const float* __restrict__ b_ih, const float* __restrict__ b_hh,
                              unsigned short* __restrict__ hi, unsigned short* __restrict__ lo,
                              float* __restrict__ bsum) {
    int idx = blockIdx.x * 256 + threadIdx.x;   // 128*2048
    int kc = idx >> 11, row = idx & 2047;
    int k = kc << 3;
    const float* src = (k < 512) ? (W_ih + (size_t)row * 512 + k)
                                 : (W_hh + (size_t)row * 512 + (k - 512));
    us8 vh, vl; split8(src, vh, vl);
    *(us8*)(hi + (size_t)idx * 8) = vh;
    *(us8*)(lo + (size_t)idx * 8) = vl;
    if (idx < NGATE) bsum[idx] = b_ih[idx] + b_hh[idx];
}

// ---------------------------------------------------------------------------
// generic blocked split: src [R][K] fp32 -> hi/lo [K/8][R][8] bf16
// grid: (ceil(R/256), K/8)
// ---------------------------------------------------------------------------
__global__ void prep_blk(const float* __restrict__ src,
                         unsigned short* __restrict__ hi, unsigned short* __restrict__ lo,
                         int R, int K) {
    int row = blockIdx.x * 256 + threadIdx.x;
    if (row >= R) return;
    int kc = blockIdx.y;
    us8 vh, vl; split8(src + (size_t)row * K + (kc << 3), vh, vl);
    size_t o = ((size_t)kc * R + row) * 8;
    *(us8*)(hi + o) = vh;
    *(us8*)(lo + o) = vl;
}

// ---------------------------------------------------------------------------
// Split-bf16 MFMA NT GEMM body. Operands pre-split bf16, K8-blocked
// [kc][rows][8]. 128x128 block tile, 4 waves (2x2 of 64x64 wave tiles),
// 32x32x16 bf16 MFMA, 2x2 frags/wave, 3-product split (hh + hl + lh).
// Staging via global_load_lds(16B). LDS kc-major [4 kc][128 row][8], 32 KB.
// MODE 3: raw fp32 C store (+ blockIdx.z split-K chunk, czstride elems)
// MODE 2: fused bias + per-row argmax via packed u64 atomicMax
// ---------------------------------------------------------------------------
template<int MODE>
__device__ __forceinline__ void mfma_blk_body(
    const unsigned short* __restrict__ Ahi, const unsigned short* __restrict__ Alo, int aRows,
    const unsigned short* __restrict__ Bhi, const unsigned short* __restrict__ Blo, int bRows,
    const float* __restrict__ bias,
    float* __restrict__ C, int ldc,
    unsigned long long* __restrict__ packed,
    int N, int K, size_t akstride, size_t bkstride, size_t czstride)
{
    __shared__ short smem[4 * 4 * 128 * 8];   // 4 halves x [4 kc][128 row][8] = 32 KB
    short* sAhi = smem;
    short* sAlo = smem + 4 * 128 * 8;
    short* sBhi = smem + 2 * 4 * 128 * 8;
    short* sBlo = smem + 3 * 4 * 128 * 8;

    const int kz = blockIdx.z;
    Ahi += kz * akstride;  Alo += kz * akstride;
    Bhi += kz * bkstride;  Blo += kz * bkstride;
    if (MODE == 3) C += kz * czstride;

    const int tid  = threadIdx.x;
    const int lane = tid & 63, wave = tid >> 6;
    const int wr = (wave & 1) * 64, wc = (wave >> 1) * 64;
    const int col = lane & 31, kh = lane >> 5;
    const int bm = blockIdx.y * 128, bn = blockIdx.x * 128;

    f32x16 acc[2][2] = {};

    for (int k0 = 0; k0 < K; k0 += 32) {
        const int kc0 = k0 >> 3;
        __syncthreads();
        // ---- stage: 2 passes x 4 waves cover 8 slabs (4 kc x 2 row-halves) per half
        #pragma unroll
        for (int p = 0; p < 2; ++p) {
            int s    = p * 4 + wave;
            int kc_l = s >> 1, rh = s & 1;
            int rl   = rh * 64 + lane;
            int lo_  = (kc_l * 128 + rh * 64) * 8;   // wave-uniform LDS short offset
            size_t ga = ((size_t)(kc0 + kc_l) * aRows + (bm + rl)) * 8;
            async_cp16(Ahi + ga, sAhi + lo_);
            async_cp16(Alo + ga, sAlo + lo_);
            int brow = bn + rl; if (brow > N - 1) brow = N - 1;
            size_t gb = ((size_t)(kc0 + kc_l) * bRows + brow) * 8;
            async_cp16(Bhi + gb, sBhi + lo_);
            async_cp16(Blo + gb, sBlo + lo_);
        }
        __syncthreads();

        // ---- two k16 steps; frag: op[row=col][k=kh*8+j] -> kc slab 2*st+kh
        #pragma unroll
        for (int st = 0; st < 2; ++st) {
            int off = (2 * st + kh) * 128 * 8;
            s8v ah0 = *(const s8v*)(sAhi + off + (wr + col) * 8);
            s8v ah1 = *(const s8v*)(sAhi + off + (wr + 32 + col) * 8);
            s8v al0 = *(const s8v*)(sAlo + off + (wr + col) * 8);
            s8v al1 = *(const s8v*)(sAlo + off + (wr + 32 + col) * 8);
            s8v bh0 = *(const s8v*)(sBhi + off + (wc + col) * 8);
            s8v bh1 = *(const s8v*)(sBhi + off + (wc + 32 + col) * 8);
            s8v bl0 = *(const s8v*)(sBlo + off + (wc + col) * 8);
            s8v bl1 = *(const s8v*)(sBlo + off + (wc + 32 + col) * 8);

            acc[0][0] = __builtin_amdgcn_mfma_f32_32x32x16_bf16(ah0, bh0, acc[0][0], 0, 0, 0);
            acc[0][1] = __builtin_amdgcn_mfma_f32_32x32x16_bf16(ah0, bh1, acc[0][1], 0, 0, 0);
            acc[1][0] = __builtin_amdgcn_mfma_f32_32x32x16_bf16(ah1, bh0, acc[1][0], 0, 0, 0);
            acc[1][1] = __builtin_amdgcn_mfma_f32_32x32x16_bf16(ah1, bh1, acc[1][1], 0, 0, 0);
            acc[0][0] = __builtin_amdgcn_mfma_f32_32x32x16_bf16(ah0, bl0, acc[0][0], 0, 0, 0);
            acc[0][1] = __builtin_amdgcn_mfma_f32_32x32x16_bf16(ah0, bl1, acc[0][1], 0, 0, 0);
            acc[1][0] = __builtin_amdgcn_mfma_f32_32x32x16_bf16(ah1, bl0, acc[1][0], 0, 0, 0);
            acc[1][1] = __builtin_amdgcn_mfma_f32_32x32x16_bf16(ah1, bl1, acc[1][1], 0, 0, 0);
            acc[0][0] = __builtin_amdgcn_mfma_f32_32x32x16_bf16(al0, bh0, acc[0][0], 0, 0, 0);
            acc[0][1] = __builtin_amdgcn_mfma_f32_32x32x16_bf16(al0, bh1, acc[0][1], 0, 0, 0);
            acc[1][0] = __builtin_amdgcn_mfma_f32_32x32x16_bf16(al1, bh0, acc[1][0], 0, 0, 0);
            acc[1][1] = __builtin_amdgcn_mfma_f32_32x32x16_bf16(al1, bh1, acc[1][1], 0, 0, 0);
        }
    }

    // C/D layout (32x32, m74/m101): col = lane&31, row = (reg&3) + 8*(reg>>2) + 4*kh
    if (MODE == 3) {
        #pragma unroll
        for (int i = 0; i < 2; ++i)
            #pragma unroll
            for (int rg = 0; rg < 4; ++rg)
                #pragma unroll
                for (int rr = 0; rr < 4; ++rr) {
                    int reg = rg * 4 + rr;
                    int m = bm + wr + i * 32 + rr + rg * 8 + kh * 4;
                    #pragma unroll
                    for (int j = 0; j < 2; ++j) {
                        int n = bn + wc + j * 32 + col;
                        if (n < N) C[(size_t)m * ldc + n] = acc[i][j][reg];
                    }
                }
    } else {
        #pragma unroll
        for (int i = 0; i < 2; ++i)
            #pragma unroll
            for (int rg = 0; rg < 4; ++rg)
                #pragma unroll
                for (int rr = 0; rr < 4; ++rr) {
                    int reg = rg * 4 + rr;
                    int m = bm + wr + i * 32 + rr + rg * 8 + kh * 4;
                    unsigned long long best = 0ull;
                    #pragma unroll
                    for (int j = 0; j < 2; ++j) {
                        int n = bn + wc + j * 32 + col;
                        if (n < N) {
                            float v = acc[i][j][reg] + bias[n];
                            unsigned int u   = __float_as_uint(v);
                            unsigned int key = (u & 0x80000000u) ? ~u : (u | 0x80000000u);
                            unsigned long long pk =
                                ((unsigned long long)key << 32) |
                                (unsigned long long)(0xFFFFFFFFu - (unsigned)n);
                            best = (pk > best) ? pk : best;
                        }
                    }
                    // reduce over 32 cols (xor<=16 stays within each 32-lane half)
                    #pragma unroll
                    for (int sdist = 1; sdist < 32; sdist <<= 1) {
                        unsigned long long o = __shfl_xor(best, sdist, 64);
                        best = (o > best) ? o : best;
                    }
                    if (col == 0) atomicMax(&packed[m], best);
                }
    }
}

__global__ __launch_bounds__(256) void k_gemm_feats(
    const unsigned short* Ahi, const unsigned short* Alo, int aRows,
    const unsigned short* Bhi, const unsigned short* Blo, int bRows,
    float* C, int ldc, int N, int K, size_t aks, size_t bks, size_t czs) {
    mfma_blk_body<3>(Ahi, Alo, aRows, Bhi, Blo, bRows, nullptr, C, ldc, nullptr, N, K, aks, bks, czs);
}
__global__ __launch_bounds__(256) void k_gemm_gates(
    const unsigned short* Ahi, const unsigned short* Alo, int aRows,
    const unsigned short* Bhi, const unsigned short* Blo, int bRows,
    float* C, int ldc, int N, int K, size_t aks, size_t bks, size_t czs) {
    mfma_blk_body<3>(Ahi, Alo, aRows, Bhi, Blo, bRows, nullptr, C, ldc, nullptr, N, K, aks, bks, czs);
}
__global__ __launch_bounds__(256) void k_logits_argmax(
    const unsigned short* Ahi, const unsigned short* Alo, int aRows,
    const unsigned short* Bhi, const unsigned short* Blo, int bRows,
    const float* bias, unsigned long long* packed, int N, int K) {
    mfma_blk_body<2>(Ahi, Alo, aRows, Bhi, Blo, bRows, bias, nullptr, 0, packed, N, K, 0, 0, 0);
}

// ---------------------------------------------------------------------------
// feats reduce: sum 8 split-K partials + bias, relu, split -> imgv blocked
// thread per (b, kc): kc in 0..63
// ---------------------------------------------------------------------------
__global__ void feats_reduce8(const float* __restrict__ part, const float* __restrict__ bias,
                              unsigned short* __restrict__ hi, unsigned short* __restrict__ lo) {
    int idx = blockIdx.x * 256 + threadIdx.x;   // 1024*64
    int b = idx >> 6, kc = idx & 63;
    int n = kc << 3;
    float v[8];
    #pragma unroll
    for (int e = 0; e < 8; ++e) v[e] = bias[n + e];
    #pragma unroll
    for (int z = 0; z < 8; ++z) {
        const float* s = part + (size_t)z * 1024 * 512 + (size_t)b * 512 + n;
        #pragma unroll
        for (int e = 0; e < 8; ++e) v[e] += s[e];
    }
    us8 vh, vl;
    #pragma unroll
    for (int e = 0; e < 8; ++e) {
        bfpair q = split2v(fmaxf(v[e], 0.f));
        vh[e] = q.hi; vl[e] = q.lo;
    }
    size_t o = ((size_t)kc * 1024 + b) * 8;
    *(us8*)(hi + o) = vh;
    *(us8*)(lo + o) = vl;
}

// ---------------------------------------------------------------------------
// LSTM pointwise: thread per (b, j8 of 8 cols). gates partials (1 or 2) +
// bsum -> c, h; h split-written to xh blocked slabs kc=64+j8; zero packed.
// ---------------------------------------------------------------------------
template<bool PRIME>
__global__ void lstm_pw_blk(const float* __restrict__ g0, const float* __restrict__ g1,
                            const float* __restrict__ bsum, float* __restrict__ cbuf,
                            unsigned short* __restrict__ xh_hi, unsigned short* __restrict__ xh_lo,
                            unsigned long long* __restrict__ packed) {
    int idx = blockIdx.x * 256 + threadIdx.x;   // 1024*64
    int b = idx >> 6, j8 = idx & 63;
    int j = j8 << 3;
    const float* g = g0 + (size_t)b * NGATE;
    float v[4][8];
    #pragma unroll
    for (int gt = 0; gt < 4; ++gt) {
        const float* s = g + gt * 512 + j;
        const float* bs = bsum + gt * 512 + j;
        #pragma unroll
        for (int e = 0; e < 8; ++e) v[gt][e] = s[e] + bs[e];
    }
    if (g1) {
        const float* h2 = g1 + (size_t)b * NGATE;
        #pragma unroll
        for (int gt = 0; gt < 4; ++gt) {
            const float* s = h2 + gt * 512 + j;
            #pragma unroll
            for (int e = 0; e < 8; ++e) v[gt][e] += s[e];
        }
    }
    float* cb = cbuf + (size_t)b * 512 + j;
    us8 vh, vl;
    #pragma unroll
    for (int e = 0; e < 8; ++e) {
        float si = 1.f / (1.f + expf(-v[0][e]));
        float sf = 1.f / (1.f + expf(-v[1][e]));
        float tg = tanhf(v[2][e]);
        float so = 1.f / (1.f + expf(-v[3][e]));
        float cn = PRIME ? (si * tg) : (sf * cb[e] + si * tg);
        cb[e] = cn;
        bfpair q = split2v(so * tanhf(cn));
        vh[e] = q.hi; vl[e] = q.lo;
    }
    size_t o = ((size_t)(64 + j8) * 1024 + b) * 8;
    *(us8*)(xh_hi + o) = vh;
    *(us8*)(xh_lo + o) = vl;
    if (j8 == 0) packed[b] = 0ull;
}

// ---------------------------------------------------------------------------
// fused finalize(t-1) + embedding gather into xh blocked slabs kc=0..63
// ---------------------------------------------------------------------------
template<int FIRST>
__global__ void gather_blk(const float* __restrict__ emb,
                           const unsigned long long* __restrict__ packed,
                           unsigned short* __restrict__ xh_hi, unsigned short* __restrict__ xh_lo,
                           int* __restrict__ out, int t) {
    int idx = blockIdx.x * 256 + threadIdx.x;   // 1024*64
    int b = idx >> 6, kc = idx & 63;
    int word;
    if (FIRST) {
        word = 1;
    } else {
        unsigned long long p = packed[b];
        int id = (int)(0xFFFFFFFFu - (unsigned)(p & 0xFFFFFFFFull));
        word = id + 2;
        if (kc == 0) out[b * SEQLEN + (t - 1)] = id;
    }
    us8 vh, vl; split8(emb + (size_t)word * 512 + (kc << 3), vh, vl);
    size_t o = ((size_t)kc * 1024 + b) * 8;
    *(us8*)(xh_hi + o) = vh;
    *(us8*)(xh_lo + o) = vl;
}

__global__ void final_out(const unsigned long long* __restrict__ packed, int* __restrict__ out) {
    int b = blockIdx.x * 256 + threadIdx.x;
    if (b < BATCH) {
        unsigned long long p = packed[b];
        out[b * SEQLEN + (SEQLEN - 1)] = (int)(0xFFFFFFFFu - (unsigned)(p & 0xFFFFFFFFull));
    }
}

extern "C" void kernel_launch(void* const* d_in, const int* in_sizes, int n_in,
                              void* d_out, int out_size, void* d_ws, size_t ws_size,
                              hipStream_t stream) {
    const float* img     = (const float*)d_in[0];
    const float* W_feats = (const float*)d_in[1];
    const float* b_feats = (const float*)d_in[2];
    const float* W_ih    = (const float*)d_in[3];
    const float* W_hh    = (const float*)d_in[4];
    const float* b_ih    = (const float*)d_in[5];
    const float* b_hh    = (const float*)d_in[6];
    const float* emb     = (const float*)d_in[7];
    const float* W_out   = (const float*)d_in[8];
    const float* b_out   = (const float*)d_in[9];
    int* out = (int*)d_out;

    // sizes in shorts (blocked halves)
    const size_t WCAT_H = (size_t)128 * 2048 * 8;   // 2,097,152
    const size_t WOUT_H = (size_t)64 * NVOCAB * 8;  // 6,142,976
    const size_t XH_H   = (size_t)128 * 1024 * 8;   // 1,048,576
    const size_t IMGV_H = (size_t)64 * 1024 * 8;    //   524,288

    char* p = (char*)d_ws;
    unsigned short* wcat_hi = (unsigned short*)p;  p += WCAT_H * 2;
    unsigned short* wcat_lo = (unsigned short*)p;  p += WCAT_H * 2;
    unsigned short* wout_hi = (unsigned short*)p;  p += WOUT_H * 2;
    unsigned short* wout_lo = (unsigned short*)p;  p += WOUT_H * 2;
    unsigned short* xh_hi   = (unsigned short*)p;  p += XH_H * 2;
    unsigned short* xh_lo   = (unsigned short*)p;  p += XH_H * 2;
    unsigned short* imgv_hi = (unsigned short*)p;  p += IMGV_H * 2;
    unsigned short* imgv_lo = (unsigned short*)p;  p += IMGV_H * 2;
    float* cbuf             = (float*)p;           p += (size_t)1024 * 512 * 4;
    float* bsum             = (float*)p;           p += (size_t)NGATE * 4;
    unsigned long long* packed = (unsigned long long*)p;  p += (size_t)1024 * 8;
    float* gates0           = (float*)p;           p += (size_t)1024 * NGATE * 4;
    float* gates1           = (float*)p;           p += (size_t)1024 * NGATE * 4;
    // ~56.6 MB total. Transient blocked feats inputs alias the (not yet
    // written) Wout region: imgb 16 MB + wfb 8 MB = 24 MB <= 24.57 MB.
    unsigned short* imgb_hi = wout_hi;                                   // 512kc x 1024 x 8
    unsigned short* imgb_lo = imgb_hi + (size_t)512 * 1024 * 8;
    unsigned short* wfb_hi  = imgb_lo + (size_t)512 * 1024 * 8;          // 512kc x 512 x 8
    unsigned short* wfb_lo  = wfb_hi  + (size_t)512 * 512 * 8;
    float* partials = gates0;   // 8 x (1024x512) fp32 = 16.78 MB = gates0+gates1

    // ---- one-time prep
    prep_wcat_blk<<<1024, 256, 0, stream>>>(W_ih, W_hh, b_ih, b_hh, wcat_hi, wcat_lo, bsum);
    prep_blk<<<dim3(4, 512), 256, 0, stream>>>(img,     imgb_hi, imgb_lo, 1024, FEATS);
    prep_blk<<<dim3(2, 512), 256, 0, stream>>>(W_feats, wfb_hi,  wfb_lo,  512,  FEATS);

    // feats: partials[z] = img(chunk z) @ W_feats(chunk z)^T, split-K x8
    k_gemm_feats<<<dim3(4, 8, 8), 256, 0, stream>>>(
        imgb_hi, imgb_lo, 1024, wfb_hi, wfb_lo, 512,
        partials, 512, 512, 512,
        (size_t)64 * 1024 * 8, (size_t)64 * 512 * 8, (size_t)1024 * 512);
    feats_reduce8<<<256, 256, 0, stream>>>(partials, b_feats, imgv_hi, imgv_lo);

    // now the feats transients are dead -> build blocked W_out in place
    prep_blk<<<dim3(47, 64), 256, 0, stream>>>(W_out, wout_hi, wout_lo, NVOCAB, 512);

    // prime LSTM: gates0 = imgv @ W_ih^T (Wcat kc 0..63)
    k_gemm_gates<<<dim3(16, 8, 1), 256, 0, stream>>>(
        imgv_hi, imgv_lo, 1024, wcat_hi, wcat_lo, 2048,
        gates0, NGATE, NGATE, 512, 0, 0, 0);
    lstm_pw_blk<true><<<256, 256, 0, stream>>>(gates0, nullptr, bsum, cbuf, xh_hi, xh_lo, packed);

    for (int t = 0; t < SEQLEN; ++t) {
        if (t == 0) gather_blk<1><<<256, 256, 0, stream>>>(emb, packed, xh_hi, xh_lo, out, t);
        else        gather_blk<0><<<256, 256, 0, stream>>>(emb, packed, xh_hi, xh_lo, out, t);

        // gates{0,1} = xh(kc chunk z) @ Wcat(kc chunk z)^T, split-K x2
        k_gemm_gates<<<dim3(16, 8, 2), 256, 0, stream>>>(
            xh_hi, xh_lo, 1024, wcat_hi, wcat_lo, 2048,
            gates0, NGATE, NGATE, 512,
            (size_t)64 * 1024 * 8, (size_t)64 * 2048 * 8, (size_t)1024 * NGATE);
        lstm_pw_blk<false><<<256, 256, 0, stream>>>(gates0, gates1, bsum, cbuf, xh_hi, xh_lo, packed);

        // logits = h @ W_out^T + b_out, fused argmax (A = h slabs: kc 64..127)
        k_logits_argmax<<<dim3(94, 8, 1), 256, 0, stream>>>(
            xh_hi + (size_t)64 * 1024 * 8, xh_lo + (size_t)64 * 1024 * 8, 1024,
            wout_hi, wout_lo, NVOCAB, b_out, packed, NVOCAB, 512);
    }
    final_out<<<4, 256, 0, stream>>>(packed, out);
}